// Round 10
// baseline (252.158 us; speedup 1.0000x reference)
//
#include <hip/hip_runtime.h>
#include <math.h>

#define BB 2
#define SEQ 2048
#define DMODEL 1024
#define NHH 16
#define DHH 64

typedef __bf16 bf16;
typedef __attribute__((ext_vector_type(8))) __bf16 bf16x8;
typedef __attribute__((ext_vector_type(4))) float f32x4;
typedef __attribute__((ext_vector_type(16))) float f32x16;

// p = exp2(s*C1 + C2) = exp(0.125*s - 4)   [static-max softmax, 0.125*|s| <~ 2.5]
#define C1f 0.18033688011112042f
#define C2f -5.770780163555854f

__device__ __forceinline__ uint32_t cvtpk_bf16(float lo, float hi) {
  uint32_t r;
  asm("v_cvt_pk_bf16_f32 %0, %1, %2" : "=v"(r) : "v"(lo), "v"(hi));
  return r;
}
__device__ __forceinline__ void pl32swap(uint32_t& a, uint32_t& b) {
  asm("v_permlane32_swap_b32 %0, %1" : "+v"(a), "+v"(b));
}

// async global -> LDS, 16B per lane. LDS dest: wave-uniform base + lane*16.
__device__ __forceinline__ void gl_lds16(const bf16* g, bf16* l) {
  __builtin_amdgcn_global_load_lds(
      (const __attribute__((address_space(1))) void*)g,
      (__attribute__((address_space(3))) void*)l, 16, 0, 0);
}

// ---------------------------------------------------------------------------
// PREP (fused): blocks [0,1024) transpose+convert the 4 weight matrices;
// blocks [1024,5120) convert the two activations.
// ---------------------------------------------------------------------------
__global__ __launch_bounds__(256) void prep(const float* __restrict__ query,
                                            const float* __restrict__ key_value,
                                            bf16* __restrict__ qbf,
                                            bf16* __restrict__ kvbf,
                                            const float* __restrict__ W0, const float* __restrict__ W1,
                                            const float* __restrict__ W2, const float* __restrict__ W3,
                                            bf16* __restrict__ O0, bf16* __restrict__ O1,
                                            bf16* __restrict__ O2, bf16* __restrict__ O3) {
  __shared__ bf16 T[64][72];
  const int bid = blockIdx.x;
  const int t = threadIdx.x;
  if (bid >= 1024) {
    const int bidc = bid - 1024;
    const float* in = (bidc >> 11) ? key_value : query;
    bf16* out = (bidc >> 11) ? kvbf : qbf;
    const int i = (bidc & 2047) * 256 + t;
    const float4* p = (const float4*)in + 2 * (size_t)i;
    float4 a = p[0], b = p[1];
    bf16x8 v;
    v[0] = (bf16)a.x; v[1] = (bf16)a.y; v[2] = (bf16)a.z; v[3] = (bf16)a.w;
    v[4] = (bf16)b.x; v[5] = (bf16)b.y; v[6] = (bf16)b.z; v[7] = (bf16)b.w;
    *((bf16x8*)out + i) = v;
    return;
  }
  const float* W; bf16* O;
  switch (bid >> 8) {
    case 0: W = W0; O = O0; break;
    case 1: W = W1; O = O1; break;
    case 2: W = W2; O = O2; break;
    default: W = W3; O = O3; break;
  }
  const int n0 = (bid & 15) * 64, k0 = ((bid >> 4) & 15) * 64;
  {
    int k = t >> 2, ns = (t & 3) * 16;
    const float* g = W + (size_t)(k0 + k) * DMODEL + n0 + ns;
#pragma unroll
    for (int q = 0; q < 4; ++q) {
      float4 f = *(const float4*)(g + 4 * q);
      T[ns + 4 * q + 0][k] = (bf16)f.x;
      T[ns + 4 * q + 1][k] = (bf16)f.y;
      T[ns + 4 * q + 2][k] = (bf16)f.z;
      T[ns + 4 * q + 3][k] = (bf16)f.w;
    }
  }
  __syncthreads();
  {
    int n = t >> 2, ks = (t & 3) * 16;
    bf16x8 a = *(const bf16x8*)&T[n][ks];
    bf16x8 b = *(const bf16x8*)&T[n][ks + 8];
    bf16* o = O + (size_t)(n0 + n) * DMODEL + k0 + ks;
    *(bf16x8*)o = a;
    *(bf16x8*)(o + 8) = b;
  }
}

// ---------------------------------------------------------------------------
// gemm_qkv: r9-exact. 256(m) x 128(n) tile, BK=64, single-buffered
// global_load_lds staging. 512 threads, 8 waves in 4x2, wave = 64x64.
// ---------------------------------------------------------------------------
__global__ __launch_bounds__(512) void gemm_qkv(const bf16* __restrict__ qbf,
                                                const bf16* __restrict__ kvbf,
                                                const bf16* __restrict__ WtQ,
                                                const bf16* __restrict__ WtK,
                                                const bf16* __restrict__ WtV,
                                                bf16* __restrict__ Qb,
                                                bf16* __restrict__ Kb,
                                                bf16* __restrict__ Vb) {
  __shared__ bf16 As[256 * 64];  // 32 KB
  __shared__ bf16 Bs[128 * 64];  // 16 KB
  const bf16 *A, *Bt; bf16* C;
  switch (blockIdx.z) {
    case 0: A = qbf; Bt = WtQ; C = Qb; break;
    case 1: A = kvbf; Bt = WtK; C = Kb; break;
    default: A = kvbf; Bt = WtV; C = Vb; break;
  }

  const int t = threadIdx.x;
  const int lane = t & 63, wave = t >> 6;
  const int l15 = lane & 15, quad = lane >> 4;
  const int bm = blockIdx.y * 256, bn = blockIdx.x * 128;
  const int wr = wave >> 1, wc = wave & 1;  // 4x2 wave grid

  const int srow = t >> 3;
  const int sc = t & 7;
  const int ca = sc ^ (srow & 7);
  const bf16* gA = A + (size_t)(bm + srow) * DMODEL + ca * 8;
  const bf16* gB = Bt + (size_t)(bn + srow) * DMODEL + ca * 8;
  const int lo = wave * 512;

  f32x4 acc[4][4] = {};

  for (int kt = 0; kt < DMODEL / 64; ++kt) {
    const int kk = kt * 64;
#pragma unroll
    for (int j = 0; j < 4; ++j)
      gl_lds16(gA + (size_t)(j * 64) * DMODEL + kk, As + lo + j * 4096);
#pragma unroll
    for (int j = 0; j < 2; ++j)
      gl_lds16(gB + (size_t)(j * 64) * DMODEL + kk, Bs + lo + j * 4096);
    __syncthreads();
#pragma unroll
    for (int ks = 0; ks < 2; ++ks) {
      bf16x8 af[4], bfr[4];
#pragma unroll
      for (int mt = 0; mt < 4; ++mt) {
        int row = wr * 64 + mt * 16 + l15;
        int s = (ks * 4 + quad) ^ (row & 7);
        af[mt] = *(const bf16x8*)&As[row * 64 + s * 8];
      }
#pragma unroll
      for (int nt = 0; nt < 4; ++nt) {
        int row = wc * 64 + nt * 16 + l15;
        int s = (ks * 4 + quad) ^ (row & 7);
        bfr[nt] = *(const bf16x8*)&Bs[row * 64 + s * 8];
      }
#pragma unroll
      for (int mt = 0; mt < 4; ++mt)
#pragma unroll
        for (int nt = 0; nt < 4; ++nt)
          acc[mt][nt] = __builtin_amdgcn_mfma_f32_16x16x32_bf16(af[mt], bfr[nt], acc[mt][nt], 0, 0, 0);
    }
    __syncthreads();
  }

#pragma unroll
  for (int mt = 0; mt < 4; ++mt)
#pragma unroll
    for (int nt = 0; nt < 4; ++nt)
#pragma unroll
      for (int r = 0; r < 4; ++r) {
        int row = bm + wr * 64 + mt * 16 + quad * 4 + r;
        int col = bn + wc * 64 + nt * 16 + l15;
        C[(size_t)row * DMODEL + col] = (bf16)acc[mt][nt][r];
      }
}

// ---------------------------------------------------------------------------
// gemm_out: r8/r9-exact 128(m) x 64(n) tile, BK=64, double-buffered.
// ---------------------------------------------------------------------------
__global__ __launch_bounds__(256, 3) void gemm_out(const bf16* __restrict__ A,
                                                   const bf16* __restrict__ Wt,
                                                   float* __restrict__ C) {
  __shared__ bf16 As0[128 * 64], Bs0[64 * 64];
  __shared__ bf16 As1[128 * 64], Bs1[64 * 64];
  const int NT = 2;

  const int t = threadIdx.x;
  const int lane = t & 63, wave = t >> 6;
  const int l15 = lane & 15, quad = lane >> 4;
  const int bm = blockIdx.y * 128, bn = blockIdx.x * (32 * NT);
  const int wr = wave >> 1, wc = wave & 1;

  const int sr8 = lane >> 3;
  const int sc = lane & 7;
  const int ca = sc ^ (sr8 & 7);
  const bf16* gA = A + (size_t)(bm + wave * 32 + sr8) * DMODEL + ca * 8;
  const bf16* gB = Wt + (size_t)(bn + wave * (8 * NT) + sr8) * DMODEL + ca * 8;
  const int loA = wave * 32 * 64;
  const int loB = wave * (8 * NT) * 64;

  f32x4 acc[4][NT] = {};

#define STAGE(KT, AS, BS)                                                 \
  {                                                                       \
    const int kk = (KT) * 64;                                             \
    _Pragma("unroll") for (int j = 0; j < 4; ++j)                         \
        gl_lds16(gA + (size_t)(j * 8) * DMODEL + kk, (AS) + loA + j * 512); \
    _Pragma("unroll") for (int j = 0; j < NT; ++j)                        \
        gl_lds16(gB + (size_t)(j * 8) * DMODEL + kk, (BS) + loB + j * 512); \
  }

#define COMPUTE(AS, BS)                                                \
  {                                                                    \
    _Pragma("unroll") for (int ks = 0; ks < 2; ++ks) {                 \
      bf16x8 af[4], bfr[NT];                                           \
      _Pragma("unroll") for (int mt = 0; mt < 4; ++mt) {               \
        int row = wr * 64 + mt * 16 + l15;                             \
        int s = (ks * 4 + quad) ^ (row & 7);                           \
        af[mt] = *(const bf16x8*)&(AS)[row * 64 + s * 8];              \
      }                                                                \
      _Pragma("unroll") for (int nt = 0; nt < NT; ++nt) {              \
        int row = wc * (16 * NT) + nt * 16 + l15;                      \
        int s = (ks * 4 + quad) ^ (row & 7);                           \
        bfr[nt] = *(const bf16x8*)&(BS)[row * 64 + s * 8];             \
      }                                                                \
      _Pragma("unroll") for (int mt = 0; mt < 4; ++mt)                 \
          _Pragma("unroll") for (int nt = 0; nt < NT; ++nt)            \
              acc[mt][nt] = __builtin_amdgcn_mfma_f32_16x16x32_bf16(   \
                  af[mt], bfr[nt], acc[mt][nt], 0, 0, 0);              \
    }                                                                  \
  }

  STAGE(0, As0, Bs0);
  __syncthreads();

  for (int kt = 0; kt < DMODEL / 64; kt += 2) {
    if (kt + 1 < DMODEL / 64) STAGE(kt + 1, As1, Bs1);
    COMPUTE(As0, Bs0);
    __syncthreads();
    if (kt + 2 < DMODEL / 64) STAGE(kt + 2, As0, Bs0);
    COMPUTE(As1, Bs1);
    __syncthreads();
  }
#undef STAGE
#undef COMPUTE

#pragma unroll
  for (int mt = 0; mt < 4; ++mt)
#pragma unroll
    for (int nt = 0; nt < NT; ++nt)
#pragma unroll
      for (int r = 0; r < 4; ++r) {
        int row = bm + wr * 64 + mt * 16 + quad * 4 + r;
        int col = bn + wc * (16 * NT) + nt * 16 + l15;
        C[(size_t)row * DMODEL + col] = acc[mt][nt][r];
      }
}

// ---------------------------------------------------------------------------
// MFMA flash attention, K-SPLIT + BIAS-MASK version:
//  * r9 structure: 8 waves, groups of 4 split the KV range; in-register P
//    (swapped 32x32 QK^T, cvt_pk + permlane32_swap); VALU lsum; padded LDS.
//  * NEW: mask folded into QK^T as a K-append bias column. K row extended
//    to 65 dims: Ks[token][64] = masked ? -30000 : 0; Q gets a synthetic
//    65th dim = 1 (qf[4], only lane-half hi==0 elem 0). s_masked then
//    underflows exp2 to EXACTLY 0.0f -> P, lsum, PV all exclude masked
//    tokens with ZERO per-element VALU mask ops (was ~96 ops/wave/chunk:
//    ballot + shifts + cndmasks -- all deleted). Cost: +2 MFMA/chunk.
//    Elems 65..79 of each row are written ZERO (0 * garbage-NaN guard).
//  * Ks rows padded to 84 elems (168B = 42 words stride: lanes l,l+16
//    share a bank = free 2-way; 80 elems would be an 8-way conflict).
// LDS 77.8 KB, 2 blocks/CU. Unmasked arithmetic bit-identical to r9.
// ---------------------------------------------------------------------------
__global__ __launch_bounds__(512, 4) void attn_mfma(const bf16* __restrict__ Qb,
                                                    const bf16* __restrict__ Kb,
                                                    const bf16* __restrict__ Vb,
                                                    const int* __restrict__ maskp,
                                                    bf16* __restrict__ Ob) {
  __shared__ bf16 Ks[2][2][64][84];  // [group][dbuf][token][d+bias]  43.0 KB
  __shared__ bf16 Vt[2][2][64][68];  // [group][dbuf][d][token]       34.8 KB

  const int blk = blockIdx.x;
  const int h = blk & 15;
  const int b = (blk >> 4) & 1;
  const int qb = blk >> 5;  // 0..15, 128-row Q tile
  const int t = threadIdx.x;
  const int wave = t >> 6, lane = t & 63;
  const int grp = wave >> 2;   // KV half
  const int w4 = wave & 3;     // q-subtile
  const int l31 = lane & 31, hi = lane >> 5;
  const int tl = t & 255;      // group-local thread id

  const int kr = tl >> 2, kq = tl & 3;
  const bf16* gK = Kb + (size_t)(b * SEQ + grp * 1024 + kr) * DMODEL + h * 64 + kq * 16;
  const int nv = (tl & 31) * 2, dc = (tl >> 5) * 8;
  const bf16* gV = Vb + (size_t)(b * SEQ + grp * 1024 + nv) * DMODEL + h * 64 + dc;
  const int* gM = maskp + b * SEQ + grp * 1024;

  // ---- stage chunk 0 into buffer 0 (K + bias column + V) ----
  {
    bf16x8 k0 = *(const bf16x8*)(gK);
    bf16x8 k1 = *(const bf16x8*)(gK + 8);
    *(bf16x8*)&Ks[grp][0][kr][kq * 16] = k0;
    *(bf16x8*)&Ks[grp][0][kr][kq * 16 + 8] = k1;
    if (tl < 64) {
      bf16x8 bv = {};
      bv[0] = gM[tl] ? (bf16)(-30000.f) : (bf16)0.f;
      bf16x8 zv = {};
      *(bf16x8*)&Ks[grp][0][tl][64] = bv;
      *(bf16x8*)&Ks[grp][0][tl][72] = zv;
    }
    bf16x8 v0 = *(const bf16x8*)(gV);
    bf16x8 v1 = *(const bf16x8*)(gV + DMODEL);
    union U { bf16x8 v; uint32_t dw[4]; } a, c;
    a.v = v0; c.v = v1;
#pragma unroll
    for (int d2 = 0; d2 < 4; ++d2) {
      *(uint32_t*)&Vt[grp][0][dc + 2 * d2 + 0][nv] = __builtin_amdgcn_perm(c.dw[d2], a.dw[d2], 0x05040100u);
      *(uint32_t*)&Vt[grp][0][dc + 2 * d2 + 1][nv] = __builtin_amdgcn_perm(c.dw[d2], a.dw[d2], 0x07060302u);
    }
  }

  // Q as B-operand fragments: lane holds Q[q=l31][d = ks*16 + hi*8 + j];
  // qf[4] = synthetic bias dim (d=64 -> 1.0, rest 0).
  bf16x8 qf[5];
#pragma unroll
  for (int ks = 0; ks < 4; ++ks) {
    const bf16* g = Qb + (size_t)(b * SEQ + qb * 128 + w4 * 32 + l31) * DMODEL +
                    h * 64 + ks * 16 + hi * 8;
    qf[ks] = *(const bf16x8*)g;
  }
  {
    bf16x8 q4 = {};
    if (hi == 0) q4[0] = (bf16)1.f;
    qf[4] = q4;
  }

  f32x16 o0 = {}, o1 = {};
  float lsum = 0.f;

  __syncthreads();  // buffer 0 ready

  for (int it = 0; it < 16; ++it) {
    const int p = it & 1;
    const bool more = (it + 1) < 16;

    // ---- issue next-chunk K/V/mask global loads (LDS-written at bottom) ----
    bf16x8 kreg0, kreg1, vreg0, vreg1;
    int mreg = 0;
    if (more) {
      const int nn = (it + 1) * 64;
      const bf16* gK2 = gK + (size_t)nn * DMODEL;
      const bf16* gV2 = gV + (size_t)nn * DMODEL;
      kreg0 = *(const bf16x8*)(gK2);
      kreg1 = *(const bf16x8*)(gK2 + 8);
      vreg0 = *(const bf16x8*)(gV2);
      vreg1 = *(const bf16x8*)(gV2 + DMODEL);
      if (tl < 64) mreg = gM[nn + tl];
    }

    // ---- S^T = K . Q^T over 5 ks-steps (step 4 = bias column) ----
    f32x16 s0v = {}, s1v = {};
#pragma unroll
    for (int ks = 0; ks < 5; ++ks) {
      const int c = (ks * 2 + hi) * 8;
      bf16x8 ka0 = *(const bf16x8*)&Ks[grp][p][l31][c];
      bf16x8 ka1 = *(const bf16x8*)&Ks[grp][p][32 + l31][c];
      s0v = __builtin_amdgcn_mfma_f32_32x32x16_bf16(ka0, qf[ks], s0v, 0, 0, 0);
      s1v = __builtin_amdgcn_mfma_f32_32x32x16_bf16(ka1, qf[ks], s1v, 0, 0, 0);
    }

    // ---- exp (masked s ~ -30000 -> exp2 underflows to exact 0) + PV ----
#pragma unroll
    for (int kt = 0; kt < 2; ++kt) {
      const f32x16 sv = kt ? s1v : s0v;
      float pm[16];
#pragma unroll
      for (int r = 0; r < 16; ++r) {
        pm[r] = __builtin_amdgcn_exp2f(sv[r] * C1f + C2f);
        lsum += pm[r];
      }
      uint32_t w01 = cvtpk_bf16(pm[0], pm[1]),  w23 = cvtpk_bf16(pm[2], pm[3]);
      uint32_t w45 = cvtpk_bf16(pm[4], pm[5]),  w67 = cvtpk_bf16(pm[6], pm[7]);
      uint32_t w89 = cvtpk_bf16(pm[8], pm[9]),  wab = cvtpk_bf16(pm[10], pm[11]);
      uint32_t wcd = cvtpk_bf16(pm[12], pm[13]), wef = cvtpk_bf16(pm[14], pm[15]);
      pl32swap(w01, w45);
      pl32swap(w23, w67);
      pl32swap(w89, wcd);
      pl32swap(wab, wef);
      union BF { uint32_t u[4]; bf16x8 v; } f0, f1;
      f0.u[0] = w01; f0.u[1] = w23; f0.u[2] = w45; f0.u[3] = w67;
      f1.u[0] = w89; f1.u[1] = wab; f1.u[2] = wcd; f1.u[3] = wef;
      {
        bf16x8 va00 = *(const bf16x8*)&Vt[grp][p][0 + l31][(kt * 2 + 0) * 16 + hi * 8];
        bf16x8 va01 = *(const bf16x8*)&Vt[grp][p][0 + l31][(kt * 2 + 1) * 16 + hi * 8];
        o0 = __builtin_amdgcn_mfma_f32_32x32x16_bf16(va00, f0.v, o0, 0, 0, 0);
        o0 = __builtin_amdgcn_mfma_f32_32x32x16_bf16(va01, f1.v, o0, 0, 0, 0);
        bf16x8 va10 = *(const bf16x8*)&Vt[grp][p][32 + l31][(kt * 2 + 0) * 16 + hi * 8];
        bf16x8 va11 = *(const bf16x8*)&Vt[grp][p][32 + l31][(kt * 2 + 1) * 16 + hi * 8];
        o1 = __builtin_amdgcn_mfma_f32_32x32x16_bf16(va10, f0.v, o1, 0, 0, 0);
        o1 = __builtin_amdgcn_mfma_f32_32x32x16_bf16(va11, f1.v, o1, 0, 0, 0);
      }
    }

    // ---- write staged chunk into buffer 1-p ----
    if (more) {
      const int q = 1 - p;
      *(bf16x8*)&Ks[grp][q][kr][kq * 16] = kreg0;
      *(bf16x8*)&Ks[grp][q][kr][kq * 16 + 8] = kreg1;
      if (tl < 64) {
        bf16x8 bv = {};
        bv[0] = mreg ? (bf16)(-30000.f) : (bf16)0.f;
        bf16x8 zv = {};
        *(bf16x8*)&Ks[grp][q][tl][64] = bv;
        *(bf16x8*)&Ks[grp][q][tl][72] = zv;
      }
      union U { bf16x8 v; uint32_t dw[4]; } a, c;
      a.v = vreg0; c.v = vreg1;
#pragma unroll
      for (int d2 = 0; d2 < 4; ++d2) {
        *(uint32_t*)&Vt[grp][q][dc + 2 * d2 + 0][nv] = __builtin_amdgcn_perm(c.dw[d2], a.dw[d2], 0x05040100u);
        *(uint32_t*)&Vt[grp][q][dc + 2 * d2 + 1][nv] = __builtin_amdgcn_perm(c.dw[d2], a.dw[d2], 0x07060302u);
      }
    }
    __syncthreads();  // buffer 1-p written, buffer p reads complete
  }

  // ---- epilogue: combine the two KV-half partials, normalize, store ----
  const float ltp = lsum + __shfl_xor(lsum, 32);

  float* sc = (float*)&Ks[0][0][0][0];
  float* scO = sc + 256;

  if (hi == 0) sc[wave * 32 + l31] = ltp;
  if (grp == 0) {
    float* dst = scO + ((size_t)(w4 * 64 + lane)) * 33;
#pragma unroll
    for (int r = 0; r < 16; ++r) {
      dst[r] = o0[r];
      dst[16 + r] = o1[r];
    }
  }
  __syncthreads();
  if (grp == 1) {
    const float ltot = sc[w4 * 32 + l31] + sc[(4 + w4) * 32 + l31];
    const float inv = 1.f / ltot;
    const float* src = scO + ((size_t)(w4 * 64 + lane)) * 33;
#pragma unroll
    for (int r = 0; r < 16; ++r) {
      o0[r] += src[r];
      o1[r] += src[16 + r];
    }
    bf16* gO = Ob + (size_t)(b * SEQ + qb * 128 + w4 * 32 + l31) * DMODEL + h * 64;
#pragma unroll
    for (int g = 0; g < 4; ++g) {
      uint2 st0, st1;
      st0.x = cvtpk_bf16(o0[4 * g + 0] * inv, o0[4 * g + 1] * inv);
      st0.y = cvtpk_bf16(o0[4 * g + 2] * inv, o0[4 * g + 3] * inv);
      st1.x = cvtpk_bf16(o1[4 * g + 0] * inv, o1[4 * g + 1] * inv);
      st1.y = cvtpk_bf16(o1[4 * g + 2] * inv, o1[4 * g + 3] * inv);
      *(uint2*)(gO + 8 * g + 4 * hi) = st0;
      *(uint2*)(gO + 32 + 8 * g + 4 * hi) = st1;
    }
  }
}

// ---------------------------------------------------------------------------
extern "C" void kernel_launch(void* const* d_in, const int* in_sizes, int n_in,
                              void* d_out, int out_size, void* d_ws, size_t ws_size,
                              hipStream_t stream) {
  (void)in_sizes; (void)n_in; (void)out_size; (void)ws_size;
  const float* query = (const float*)d_in[0];
  const float* key_value = (const float*)d_in[1];
  const int* mask = (const int*)d_in[2];
  const float* W_Q = (const float*)d_in[3];
  const float* W_K = (const float*)d_in[4];
  const float* W_V = (const float*)d_in[5];
  const float* W_O = (const float*)d_in[6];
  float* out = (float*)d_out;

  const size_t TOK = (size_t)BB * SEQ;  // 4096
  const size_t TE = TOK * DMODEL;       // 4,194,304 elems
  char* w = (char*)d_ws;
  bf16* qbf = (bf16*)w;   w += TE * 2;
  bf16* kvbf = (bf16*)w;  w += TE * 2;
  bf16* WtQ = (bf16*)w;   w += (size_t)DMODEL * DMODEL * 2;
  bf16* WtK = (bf16*)w;   w += (size_t)DMODEL * DMODEL * 2;
  bf16* WtV = (bf16*)w;   w += (size_t)DMODEL * DMODEL * 2;
  bf16* WtO = (bf16*)w;   w += (size_t)DMODEL * DMODEL * 2;
  bf16* Qbuf = (bf16*)w;  w += TE * 2;
  bf16* Kbuf = (bf16*)w;  w += TE * 2;
  bf16* Vbuf = (bf16*)w;  w += TE * 2;
  bf16* Obuf = (bf16*)w;  w += TE * 2;

  prep<<<5120, 256, 0, stream>>>(query, key_value, qbf, kvbf,
                                 W_Q, W_K, W_V, W_O, WtQ, WtK, WtV, WtO);

  gemm_qkv<<<dim3(DMODEL / 128, TOK / 256, 3), 512, 0, stream>>>(qbf, kvbf, WtQ, WtK, WtV,
                                                                 Qbuf, Kbuf, Vbuf);

  attn_mfma<<<BB * NHH * (SEQ / 128), 512, 0, stream>>>(Qbuf, Kbuf, Vbuf, mask, Obuf);

  gemm_out<<<dim3(DMODEL / 64, TOK / 128), 256, 0, stream>>>(Obuf, WtO, out);
}

// Round 11
// 192.897 us; speedup vs baseline: 1.3072x; 1.3072x over previous
//
#include <hip/hip_runtime.h>
#include <math.h>

#define BB 2
#define SEQ 2048
#define DMODEL 1024
#define NHH 16
#define DHH 64

typedef __bf16 bf16;
typedef __attribute__((ext_vector_type(8))) __bf16 bf16x8;
typedef __attribute__((ext_vector_type(4))) float f32x4;
typedef __attribute__((ext_vector_type(16))) float f32x16;

// p = exp2(s*C1 + C2) = exp(0.125*s - 4)   [static-max softmax, 0.125*|s| <~ 2.5]
#define C1f 0.18033688011112042f
#define C2f -5.770780163555854f

__device__ __forceinline__ uint32_t cvtpk_bf16(float lo, float hi) {
  uint32_t r;
  asm("v_cvt_pk_bf16_f32 %0, %1, %2" : "=v"(r) : "v"(lo), "v"(hi));
  return r;
}
__device__ __forceinline__ void pl32swap(uint32_t& a, uint32_t& b) {
  asm("v_permlane32_swap_b32 %0, %1" : "+v"(a), "+v"(b));
}

// async global -> LDS, 16B per lane. LDS dest: wave-uniform base + lane*16.
__device__ __forceinline__ void gl_lds16(const bf16* g, bf16* l) {
  __builtin_amdgcn_global_load_lds(
      (const __attribute__((address_space(1))) void*)g,
      (__attribute__((address_space(3))) void*)l, 16, 0, 0);
}

// ---------------------------------------------------------------------------
// PREP (fused): blocks [0,1024) transpose+convert the 4 weight matrices;
// blocks [1024,5120) convert the two activations.
// ---------------------------------------------------------------------------
__global__ __launch_bounds__(256) void prep(const float* __restrict__ query,
                                            const float* __restrict__ key_value,
                                            bf16* __restrict__ qbf,
                                            bf16* __restrict__ kvbf,
                                            const float* __restrict__ W0, const float* __restrict__ W1,
                                            const float* __restrict__ W2, const float* __restrict__ W3,
                                            bf16* __restrict__ O0, bf16* __restrict__ O1,
                                            bf16* __restrict__ O2, bf16* __restrict__ O3) {
  __shared__ bf16 T[64][72];
  const int bid = blockIdx.x;
  const int t = threadIdx.x;
  if (bid >= 1024) {
    const int bidc = bid - 1024;
    const float* in = (bidc >> 11) ? key_value : query;
    bf16* out = (bidc >> 11) ? kvbf : qbf;
    const int i = (bidc & 2047) * 256 + t;
    const float4* p = (const float4*)in + 2 * (size_t)i;
    float4 a = p[0], b = p[1];
    bf16x8 v;
    v[0] = (bf16)a.x; v[1] = (bf16)a.y; v[2] = (bf16)a.z; v[3] = (bf16)a.w;
    v[4] = (bf16)b.x; v[5] = (bf16)b.y; v[6] = (bf16)b.z; v[7] = (bf16)b.w;
    *((bf16x8*)out + i) = v;
    return;
  }
  const float* W; bf16* O;
  switch (bid >> 8) {
    case 0: W = W0; O = O0; break;
    case 1: W = W1; O = O1; break;
    case 2: W = W2; O = O2; break;
    default: W = W3; O = O3; break;
  }
  const int n0 = (bid & 15) * 64, k0 = ((bid >> 4) & 15) * 64;
  {
    int k = t >> 2, ns = (t & 3) * 16;
    const float* g = W + (size_t)(k0 + k) * DMODEL + n0 + ns;
#pragma unroll
    for (int q = 0; q < 4; ++q) {
      float4 f = *(const float4*)(g + 4 * q);
      T[ns + 4 * q + 0][k] = (bf16)f.x;
      T[ns + 4 * q + 1][k] = (bf16)f.y;
      T[ns + 4 * q + 2][k] = (bf16)f.z;
      T[ns + 4 * q + 3][k] = (bf16)f.w;
    }
  }
  __syncthreads();
  {
    int n = t >> 2, ks = (t & 3) * 16;
    bf16x8 a = *(const bf16x8*)&T[n][ks];
    bf16x8 b = *(const bf16x8*)&T[n][ks + 8];
    bf16* o = O + (size_t)(n0 + n) * DMODEL + k0 + ks;
    *(bf16x8*)o = a;
    *(bf16x8*)(o + 8) = b;
  }
}

// ---------------------------------------------------------------------------
// gemm_qkv: r9 body + XCD-AWARE TILE SWIZZLE. 256(m) x 128(n) tile, BK=64,
// single-buffered global_load_lds staging. 512 threads, 8 waves in 4x2.
// Swizzle: hardware XCD = linear_block_id % 8 (round-robin). Remap so each
// XCD owns 2 COMPLETE y-rows (2 A-panels + all 8 B-panels): per-XCD L2
// traffic 8.25 MB -> 3 MB per z-slice (2.75x). Bijective: grid 8x16 = 128
// blocks, (xcd, j) -> (ly, lx) partitions exactly.
// ---------------------------------------------------------------------------
__global__ __launch_bounds__(512) void gemm_qkv(const bf16* __restrict__ qbf,
                                                const bf16* __restrict__ kvbf,
                                                const bf16* __restrict__ WtQ,
                                                const bf16* __restrict__ WtK,
                                                const bf16* __restrict__ WtV,
                                                bf16* __restrict__ Qb,
                                                bf16* __restrict__ Kb,
                                                bf16* __restrict__ Vb) {
  __shared__ bf16 As[256 * 64];  // 32 KB
  __shared__ bf16 Bs[128 * 64];  // 16 KB
  const bf16 *A, *Bt; bf16* C;
  switch (blockIdx.z) {
    case 0: A = qbf; Bt = WtQ; C = Qb; break;
    case 1: A = kvbf; Bt = WtK; C = Kb; break;
    default: A = kvbf; Bt = WtV; C = Vb; break;
  }

  const int t = threadIdx.x;
  const int lane = t & 63, wave = t >> 6;
  const int l15 = lane & 15, quad = lane >> 4;
  // XCD-aware remap of (x,y) tile coordinates
  const int flat = blockIdx.y * 8 + blockIdx.x;  // 0..127, == linear id % 128
  const int xcd = flat & 7, j = flat >> 3;       // j 0..15
  const int ly = 2 * xcd + (j >> 3);             // 0..15
  const int lx = j & 7;                          // 0..7
  const int bm = ly * 256, bn = lx * 128;
  const int wr = wave >> 1, wc = wave & 1;  // 4x2 wave grid

  const int srow = t >> 3;
  const int sc = t & 7;
  const int ca = sc ^ (srow & 7);
  const bf16* gA = A + (size_t)(bm + srow) * DMODEL + ca * 8;
  const bf16* gB = Bt + (size_t)(bn + srow) * DMODEL + ca * 8;
  const int lo = wave * 512;

  f32x4 acc[4][4] = {};

  for (int kt = 0; kt < DMODEL / 64; ++kt) {
    const int kk = kt * 64;
#pragma unroll
    for (int j2 = 0; j2 < 4; ++j2)
      gl_lds16(gA + (size_t)(j2 * 64) * DMODEL + kk, As + lo + j2 * 4096);
#pragma unroll
    for (int j2 = 0; j2 < 2; ++j2)
      gl_lds16(gB + (size_t)(j2 * 64) * DMODEL + kk, Bs + lo + j2 * 4096);
    __syncthreads();
#pragma unroll
    for (int ks = 0; ks < 2; ++ks) {
      bf16x8 af[4], bfr[4];
#pragma unroll
      for (int mt = 0; mt < 4; ++mt) {
        int row = wr * 64 + mt * 16 + l15;
        int s = (ks * 4 + quad) ^ (row & 7);
        af[mt] = *(const bf16x8*)&As[row * 64 + s * 8];
      }
#pragma unroll
      for (int nt = 0; nt < 4; ++nt) {
        int row = wc * 64 + nt * 16 + l15;
        int s = (ks * 4 + quad) ^ (row & 7);
        bfr[nt] = *(const bf16x8*)&Bs[row * 64 + s * 8];
      }
#pragma unroll
      for (int mt = 0; mt < 4; ++mt)
#pragma unroll
        for (int nt = 0; nt < 4; ++nt)
          acc[mt][nt] = __builtin_amdgcn_mfma_f32_16x16x32_bf16(af[mt], bfr[nt], acc[mt][nt], 0, 0, 0);
    }
    __syncthreads();
  }

#pragma unroll
  for (int mt = 0; mt < 4; ++mt)
#pragma unroll
    for (int nt = 0; nt < 4; ++nt)
#pragma unroll
      for (int r = 0; r < 4; ++r) {
        int row = bm + wr * 64 + mt * 16 + quad * 4 + r;
        int col = bn + wc * 64 + nt * 16 + l15;
        C[(size_t)row * DMODEL + col] = (bf16)acc[mt][nt][r];
      }
}

// ---------------------------------------------------------------------------
// gemm_out: r9 body + XCD-AWARE TILE SWIZZLE. 128(m) x 64(n) tile, BK=64,
// double-buffered. Grid 16x32 = 512 blocks; each XCD owns 4 complete
// y-rows (4 A-panels + all 16 B-panels): per-XCD L2 traffic 8.25 -> 3 MB.
// ---------------------------------------------------------------------------
__global__ __launch_bounds__(256, 3) void gemm_out(const bf16* __restrict__ A,
                                                   const bf16* __restrict__ Wt,
                                                   float* __restrict__ C) {
  __shared__ bf16 As0[128 * 64], Bs0[64 * 64];
  __shared__ bf16 As1[128 * 64], Bs1[64 * 64];
  const int NT = 2;

  const int t = threadIdx.x;
  const int lane = t & 63, wave = t >> 6;
  const int l15 = lane & 15, quad = lane >> 4;
  // XCD-aware remap of (x,y) tile coordinates
  const int flat = blockIdx.y * 16 + blockIdx.x;  // 0..511
  const int xcd = flat & 7, j = flat >> 3;        // j 0..63
  const int ly = 4 * xcd + (j >> 4);              // 0..31
  const int lx = j & 15;                          // 0..15
  const int bm = ly * 128, bn = lx * (32 * NT);
  const int wr = wave >> 1, wc = wave & 1;

  const int sr8 = lane >> 3;
  const int sc = lane & 7;
  const int ca = sc ^ (sr8 & 7);
  const bf16* gA = A + (size_t)(bm + wave * 32 + sr8) * DMODEL + ca * 8;
  const bf16* gB = Wt + (size_t)(bn + wave * (8 * NT) + sr8) * DMODEL + ca * 8;
  const int loA = wave * 32 * 64;
  const int loB = wave * (8 * NT) * 64;

  f32x4 acc[4][NT] = {};

#define STAGE(KT, AS, BS)                                                 \
  {                                                                       \
    const int kk = (KT) * 64;                                             \
    _Pragma("unroll") for (int j2 = 0; j2 < 4; ++j2)                      \
        gl_lds16(gA + (size_t)(j2 * 8) * DMODEL + kk, (AS) + loA + j2 * 512); \
    _Pragma("unroll") for (int j2 = 0; j2 < NT; ++j2)                     \
        gl_lds16(gB + (size_t)(j2 * 8) * DMODEL + kk, (BS) + loB + j2 * 512); \
  }

#define COMPUTE(AS, BS)                                                \
  {                                                                    \
    _Pragma("unroll") for (int ks = 0; ks < 2; ++ks) {                 \
      bf16x8 af[4], bfr[NT];                                           \
      _Pragma("unroll") for (int mt = 0; mt < 4; ++mt) {               \
        int row = wr * 64 + mt * 16 + l15;                             \
        int s = (ks * 4 + quad) ^ (row & 7);                           \
        af[mt] = *(const bf16x8*)&(AS)[row * 64 + s * 8];              \
      }                                                                \
      _Pragma("unroll") for (int nt = 0; nt < NT; ++nt) {              \
        int row = wc * (16 * NT) + nt * 16 + l15;                      \
        int s = (ks * 4 + quad) ^ (row & 7);                           \
        bfr[nt] = *(const bf16x8*)&(BS)[row * 64 + s * 8];             \
      }                                                                \
      _Pragma("unroll") for (int mt = 0; mt < 4; ++mt)                 \
          _Pragma("unroll") for (int nt = 0; nt < NT; ++nt)            \
              acc[mt][nt] = __builtin_amdgcn_mfma_f32_16x16x32_bf16(   \
                  af[mt], bfr[nt], acc[mt][nt], 0, 0, 0);              \
    }                                                                  \
  }

  STAGE(0, As0, Bs0);
  __syncthreads();

  for (int kt = 0; kt < DMODEL / 64; kt += 2) {
    if (kt + 1 < DMODEL / 64) STAGE(kt + 1, As1, Bs1);
    COMPUTE(As0, Bs0);
    __syncthreads();
    if (kt + 2 < DMODEL / 64) STAGE(kt + 2, As0, Bs0);
    COMPUTE(As1, Bs1);
    __syncthreads();
  }
#undef STAGE
#undef COMPUTE

#pragma unroll
  for (int mt = 0; mt < 4; ++mt)
#pragma unroll
    for (int nt = 0; nt < NT; ++nt)
#pragma unroll
      for (int r = 0; r < 4; ++r) {
        int row = bm + wr * 64 + mt * 16 + quad * 4 + r;
        int col = bn + wc * (16 * NT) + nt * 16 + l15;
        C[(size_t)row * DMODEL + col] = acc[mt][nt][r];
      }
}

// ---------------------------------------------------------------------------
// MFMA flash attention, K-SPLIT version — EXACT r9 kernel (59.4 us, passed):
// 8 waves; groups of 4 split the KV range; in-register P (swapped 32x32
// QK^T, cvt_pk + permlane32_swap); ballot mask + VALU lsum; padded LDS.
// r10's bias-column variant spilled to scratch (FETCH 12->86 MB) — closed.
// ---------------------------------------------------------------------------
__global__ __launch_bounds__(512, 4) void attn_mfma(const bf16* __restrict__ Qb,
                                                    const bf16* __restrict__ Kb,
                                                    const bf16* __restrict__ Vb,
                                                    const int* __restrict__ maskp,
                                                    bf16* __restrict__ Ob) {
  __shared__ bf16 Ks[2][2][64][68];  // [group][dbuf][token][d]   34.8 KB
  __shared__ bf16 Vt[2][2][64][68];  // [group][dbuf][d][token]   34.8 KB

  const int blk = blockIdx.x;
  const int h = blk & 15;
  const int b = (blk >> 4) & 1;
  const int qb = blk >> 5;  // 0..15, 128-row Q tile
  const int t = threadIdx.x;
  const int wave = t >> 6, lane = t & 63;
  const int grp = wave >> 2;   // KV half
  const int w4 = wave & 3;     // q-subtile
  const int l31 = lane & 31, hi = lane >> 5;
  const int tl = t & 255;      // group-local thread id

  const int kr = tl >> 2, kq = tl & 3;
  const bf16* gK = Kb + (size_t)(b * SEQ + grp * 1024 + kr) * DMODEL + h * 64 + kq * 16;
  const int nv = (tl & 31) * 2, dc = (tl >> 5) * 8;
  const bf16* gV = Vb + (size_t)(b * SEQ + grp * 1024 + nv) * DMODEL + h * 64 + dc;
  const int* gM = maskp + b * SEQ + grp * 1024;

  // ---- stage chunk 0 into buffer 0 ----
  {
    bf16x8 k0 = *(const bf16x8*)(gK);
    bf16x8 k1 = *(const bf16x8*)(gK + 8);
    *(bf16x8*)&Ks[grp][0][kr][kq * 16] = k0;
    *(bf16x8*)&Ks[grp][0][kr][kq * 16 + 8] = k1;
    bf16x8 v0 = *(const bf16x8*)(gV);
    bf16x8 v1 = *(const bf16x8*)(gV + DMODEL);
    union U { bf16x8 v; uint32_t dw[4]; } a, c;
    a.v = v0; c.v = v1;
#pragma unroll
    for (int d2 = 0; d2 < 4; ++d2) {
      *(uint32_t*)&Vt[grp][0][dc + 2 * d2 + 0][nv] = __builtin_amdgcn_perm(c.dw[d2], a.dw[d2], 0x05040100u);
      *(uint32_t*)&Vt[grp][0][dc + 2 * d2 + 1][nv] = __builtin_amdgcn_perm(c.dw[d2], a.dw[d2], 0x07060302u);
    }
  }
  int mcur = gM[lane];

  bf16x8 qf[4];
#pragma unroll
  for (int ks = 0; ks < 4; ++ks) {
    const bf16* g = Qb + (size_t)(b * SEQ + qb * 128 + w4 * 32 + l31) * DMODEL +
                    h * 64 + ks * 16 + hi * 8;
    qf[ks] = *(const bf16x8*)g;
  }

  f32x16 o0 = {}, o1 = {};
  float lsum = 0.f;

  __syncthreads();  // buffer 0 ready

  for (int it = 0; it < 16; ++it) {
    const int p = it & 1;
    const bool more = (it + 1) < 16;

    bf16x8 kreg0, kreg1, vreg0, vreg1;
    int mnext = 0;
    if (more) {
      const int nn = (it + 1) * 64;
      const bf16* gK2 = gK + (size_t)nn * DMODEL;
      const bf16* gV2 = gV + (size_t)nn * DMODEL;
      kreg0 = *(const bf16x8*)(gK2);
      kreg1 = *(const bf16x8*)(gK2 + 8);
      vreg0 = *(const bf16x8*)(gV2);
      vreg1 = *(const bf16x8*)(gV2 + DMODEL);
      mnext = gM[nn + lane];
    }

    f32x16 s0v = {}, s1v = {};
#pragma unroll
    for (int ks = 0; ks < 4; ++ks) {
      const int c = (ks * 2 + hi) * 8;
      bf16x8 ka0 = *(const bf16x8*)&Ks[grp][p][l31][c];
      bf16x8 ka1 = *(const bf16x8*)&Ks[grp][p][32 + l31][c];
      s0v = __builtin_amdgcn_mfma_f32_32x32x16_bf16(ka0, qf[ks], s0v, 0, 0, 0);
      s1v = __builtin_amdgcn_mfma_f32_32x32x16_bf16(ka1, qf[ks], s1v, 0, 0, 0);
    }

    const unsigned long long mb = __ballot(mcur == 0);

#pragma unroll
    for (int kt = 0; kt < 2; ++kt) {
      const f32x16 sv = kt ? s1v : s0v;
      const uint32_t ml = (uint32_t)(mb >> (kt * 32 + 4 * hi));
      float pm[16];
#pragma unroll
      for (int r = 0; r < 16; ++r) {
        const int bitc = (r & 3) + 8 * (r >> 2);
        float pex = __builtin_amdgcn_exp2f(sv[r] * C1f + C2f);
        pm[r] = ((ml >> bitc) & 1u) ? pex : 0.f;
        lsum += pm[r];
      }
      uint32_t w01 = cvtpk_bf16(pm[0], pm[1]),  w23 = cvtpk_bf16(pm[2], pm[3]);
      uint32_t w45 = cvtpk_bf16(pm[4], pm[5]),  w67 = cvtpk_bf16(pm[6], pm[7]);
      uint32_t w89 = cvtpk_bf16(pm[8], pm[9]),  wab = cvtpk_bf16(pm[10], pm[11]);
      uint32_t wcd = cvtpk_bf16(pm[12], pm[13]), wef = cvtpk_bf16(pm[14], pm[15]);
      pl32swap(w01, w45);
      pl32swap(w23, w67);
      pl32swap(w89, wcd);
      pl32swap(wab, wef);
      union BF { uint32_t u[4]; bf16x8 v; } f0, f1;
      f0.u[0] = w01; f0.u[1] = w23; f0.u[2] = w45; f0.u[3] = w67;
      f1.u[0] = w89; f1.u[1] = wab; f1.u[2] = wcd; f1.u[3] = wef;
      {
        bf16x8 va00 = *(const bf16x8*)&Vt[grp][p][0 + l31][(kt * 2 + 0) * 16 + hi * 8];
        bf16x8 va01 = *(const bf16x8*)&Vt[grp][p][0 + l31][(kt * 2 + 1) * 16 + hi * 8];
        o0 = __builtin_amdgcn_mfma_f32_32x32x16_bf16(va00, f0.v, o0, 0, 0, 0);
        o0 = __builtin_amdgcn_mfma_f32_32x32x16_bf16(va01, f1.v, o0, 0, 0, 0);
        bf16x8 va10 = *(const bf16x8*)&Vt[grp][p][32 + l31][(kt * 2 + 0) * 16 + hi * 8];
        bf16x8 va11 = *(const bf16x8*)&Vt[grp][p][32 + l31][(kt * 2 + 1) * 16 + hi * 8];
        o1 = __builtin_amdgcn_mfma_f32_32x32x16_bf16(va10, f0.v, o1, 0, 0, 0);
        o1 = __builtin_amdgcn_mfma_f32_32x32x16_bf16(va11, f1.v, o1, 0, 0, 0);
      }
    }

    if (more) {
      const int q = 1 - p;
      *(bf16x8*)&Ks[grp][q][kr][kq * 16] = kreg0;
      *(bf16x8*)&Ks[grp][q][kr][kq * 16 + 8] = kreg1;
      union U { bf16x8 v; uint32_t dw[4]; } a, c;
      a.v = vreg0; c.v = vreg1;
#pragma unroll
      for (int d2 = 0; d2 < 4; ++d2) {
        *(uint32_t*)&Vt[grp][q][dc + 2 * d2 + 0][nv] = __builtin_amdgcn_perm(c.dw[d2], a.dw[d2], 0x05040100u);
        *(uint32_t*)&Vt[grp][q][dc + 2 * d2 + 1][nv] = __builtin_amdgcn_perm(c.dw[d2], a.dw[d2], 0x07060302u);
      }
    }
    mcur = mnext;
    __syncthreads();  // buffer 1-p written, buffer p reads complete
  }

  // ---- epilogue: combine the two KV-half partials, normalize, store ----
  const float ltp = lsum + __shfl_xor(lsum, 32);

  float* sc2 = (float*)&Ks[0][0][0][0];
  float* scO = sc2 + 256;

  if (hi == 0) sc2[wave * 32 + l31] = ltp;
  if (grp == 0) {
    float* dst = scO + ((size_t)(w4 * 64 + lane)) * 33;
#pragma unroll
    for (int r = 0; r < 16; ++r) {
      dst[r] = o0[r];
      dst[16 + r] = o1[r];
    }
  }
  __syncthreads();
  if (grp == 1) {
    const float ltot = sc2[w4 * 32 + l31] + sc2[(4 + w4) * 32 + l31];
    const float inv = 1.f / ltot;
    const float* src = scO + ((size_t)(w4 * 64 + lane)) * 33;
#pragma unroll
    for (int r = 0; r < 16; ++r) {
      o0[r] += src[r];
      o1[r] += src[16 + r];
    }
    bf16* gO = Ob + (size_t)(b * SEQ + qb * 128 + w4 * 32 + l31) * DMODEL + h * 64;
#pragma unroll
    for (int g = 0; g < 4; ++g) {
      uint2 st0, st1;
      st0.x = cvtpk_bf16(o0[4 * g + 0] * inv, o0[4 * g + 1] * inv);
      st0.y = cvtpk_bf16(o0[4 * g + 2] * inv, o0[4 * g + 3] * inv);
      st1.x = cvtpk_bf16(o1[4 * g + 0] * inv, o1[4 * g + 1] * inv);
      st1.y = cvtpk_bf16(o1[4 * g + 2] * inv, o1[4 * g + 3] * inv);
      *(uint2*)(gO + 8 * g + 4 * hi) = st0;
      *(uint2*)(gO + 32 + 8 * g + 4 * hi) = st1;
    }
  }
}

// ---------------------------------------------------------------------------
extern "C" void kernel_launch(void* const* d_in, const int* in_sizes, int n_in,
                              void* d_out, int out_size, void* d_ws, size_t ws_size,
                              hipStream_t stream) {
  (void)in_sizes; (void)n_in; (void)out_size; (void)ws_size;
  const float* query = (const float*)d_in[0];
  const float* key_value = (const float*)d_in[1];
  const int* mask = (const int*)d_in[2];
  const float* W_Q = (const float*)d_in[3];
  const float* W_K = (const float*)d_in[4];
  const float* W_V = (const float*)d_in[5];
  const float* W_O = (const float*)d_in[6];
  float* out = (float*)d_out;

  const size_t TOK = (size_t)BB * SEQ;  // 4096
  const size_t TE = TOK * DMODEL;       // 4,194,304 elems
  char* w = (char*)d_ws;
  bf16* qbf = (bf16*)w;   w += TE * 2;
  bf16* kvbf = (bf16*)w;  w += TE * 2;
  bf16* WtQ = (bf16*)w;   w += (size_t)DMODEL * DMODEL * 2;
  bf16* WtK = (bf16*)w;   w += (size_t)DMODEL * DMODEL * 2;
  bf16* WtV = (bf16*)w;   w += (size_t)DMODEL * DMODEL * 2;
  bf16* WtO = (bf16*)w;   w += (size_t)DMODEL * DMODEL * 2;
  bf16* Qbuf = (bf16*)w;  w += TE * 2;
  bf16* Kbuf = (bf16*)w;  w += TE * 2;
  bf16* Vbuf = (bf16*)w;  w += TE * 2;
  bf16* Obuf = (bf16*)w;  w += TE * 2;

  prep<<<5120, 256, 0, stream>>>(query, key_value, qbf, kvbf,
                                 W_Q, W_K, W_V, W_O, WtQ, WtK, WtV, WtO);

  gemm_qkv<<<dim3(DMODEL / 128, TOK / 256, 3), 512, 0, stream>>>(qbf, kvbf, WtQ, WtK, WtV,
                                                                 Qbuf, Kbuf, Vbuf);

  attn_mfma<<<BB * NHH * (SEQ / 128), 512, 0, stream>>>(Qbuf, Kbuf, Vbuf, mask, Obuf);

  gemm_out<<<dim3(DMODEL / 64, TOK / 128), 256, 0, stream>>>(Obuf, WtO, out);
}